// Round 2
// baseline (3000.594 us; speedup 1.0000x reference)
//
#include <hip/hip_runtime.h>

#define D 64            // FEAT
#define ALPHA_ 0.1f
#define BETA1 0.9f      // 1 - ALPHA

// ---------------------------------------------------------------- relu: x = max(h,0)
__global__ void relu_k(const float* __restrict__ h, float* __restrict__ x, int n) {
    int i = blockIdx.x * blockDim.x + threadIdx.x;
    if (i < n) x[i] = fmaxf(h[i], 0.0f);
}

// ---------------------------------------------------------------- degree counting (float histogram; exact for counts < 2^24)
__global__ void deg_k(const int* __restrict__ src, const int* __restrict__ dst,
                      float* __restrict__ dout, float* __restrict__ din, int E) {
    int e = blockIdx.x * blockDim.x + threadIdx.x;
    if (e < E) {
        atomicAdd(&dout[src[e]], 1.0f);
        atomicAdd(&din[dst[e]], 1.0f);
    }
}

// ---------------------------------------------------------------- deg -> clip(deg,1)^-0.5 (in place)
__global__ void norm_k(float* __restrict__ dout, float* __restrict__ din, int N) {
    int i = blockIdx.x * blockDim.x + threadIdx.x;
    if (i < N) {
        dout[i] = 1.0f / sqrtf(fmaxf(dout[i], 1.0f));
        din[i]  = 1.0f / sqrtf(fmaxf(din[i],  1.0f));
    }
}

// ---------------------------------------------------------------- scan stage 1: per-256-block exclusive scan of (int)degf
__global__ void scan1_k(const float* __restrict__ degf, int* __restrict__ excl,
                        int* __restrict__ bsum, int N) {
    __shared__ int tmp[256];
    int tid = threadIdx.x;
    int i = blockIdx.x * 256 + tid;
    int v = (i < N) ? (int)degf[i] : 0;
    tmp[tid] = v;
    __syncthreads();
    for (int off = 1; off < 256; off <<= 1) {
        int t = (tid >= off) ? tmp[tid - off] : 0;
        __syncthreads();
        tmp[tid] += t;
        __syncthreads();
    }
    if (i < N) excl[i] = tmp[tid] - v;           // exclusive within block
    if (tid == 255) bsum[blockIdx.x] = tmp[255]; // block total
}

// ---------------------------------------------------------------- scan stage 2: single block scans block sums (nb <= 512)
__global__ void scan2_k(int* __restrict__ bsum, int nb) {
    __shared__ int tmp[512];
    int i = threadIdx.x;
    int v = (i < nb) ? bsum[i] : 0;
    tmp[i] = v;
    __syncthreads();
    for (int off = 1; off < 512; off <<= 1) {
        int t = (i >= off) ? tmp[i - off] : 0;
        __syncthreads();
        tmp[i] += t;
        __syncthreads();
    }
    if (i < nb) bsum[i] = tmp[i] - v; // exclusive
}

// ---------------------------------------------------------------- scan stage 3: add block offsets; init fill pointers
__global__ void scan3_k(int* __restrict__ rowptr, int* __restrict__ fillptr,
                        const int* __restrict__ bsum, int N) {
    int i = blockIdx.x * blockDim.x + threadIdx.x;
    if (i < N) {
        int r = rowptr[i] + bsum[i >> 8];
        rowptr[i] = r;
        fillptr[i] = r;
    }
}

// ---------------------------------------------------------------- reorder edges by dst; precompute folded edge weight
// After this, fillptr[d] == rowptr[d] + indeg(d)  (used as row end in pull_k)
__global__ void reorder_k(const int* __restrict__ src, const int* __restrict__ dst,
                          const float* __restrict__ nout, const float* __restrict__ nin,
                          int* __restrict__ fillptr, int* __restrict__ ssrc,
                          float* __restrict__ sw, int E) {
    int e = blockIdx.x * blockDim.x + threadIdx.x;
    if (e < E) {
        int s = src[e], d = dst[e];
        int pos = atomicAdd(&fillptr[d], 1);
        ssrc[pos] = s;
        sw[pos] = BETA1 * nout[s] * nin[d];
    }
}

// ---------------------------------------------------------------- pull aggregation: one wave64 per node, lane = feature
// out[n] = 0.1*x[n] + sum_{e in-edges(n)} w_e * feat[src_e]      (no atomics)
__global__ void pull_k(const int* __restrict__ rowptr, const int* __restrict__ rowend,
                       const int* __restrict__ ssrc, const float* __restrict__ sw,
                       const float* __restrict__ feat, const float* __restrict__ x,
                       float* __restrict__ out, int N) {
    int wid = (blockIdx.x * blockDim.x + threadIdx.x) >> 6;
    int lane = threadIdx.x & 63;
    if (wid >= N) return;
    int start = rowptr[wid];
    int end = rowend[wid];
    float acc = ALPHA_ * x[(size_t)wid * D + lane];
    int k = start;
    for (; k + 4 <= end; k += 4) {
        int s0 = ssrc[k], s1 = ssrc[k + 1], s2 = ssrc[k + 2], s3 = ssrc[k + 3];
        float w0 = sw[k], w1 = sw[k + 1], w2 = sw[k + 2], w3 = sw[k + 3];
        float f0 = feat[(size_t)s0 * D + lane];
        float f1 = feat[(size_t)s1 * D + lane];
        float f2 = feat[(size_t)s2 * D + lane];
        float f3 = feat[(size_t)s3 * D + lane];
        acc += w0 * f0;
        acc += w1 * f1;
        acc += w2 * f2;
        acc += w3 * f3;
    }
    for (; k < end; ++k) acc += sw[k] * feat[(size_t)ssrc[k] * D + lane];
    out[(size_t)wid * D + lane] = acc;
}

// ---------------------------------------------------------------- fusion: W1 in LDS, 16 nodes per block, 1 atomic/block
__global__ void fusion_k(const float* __restrict__ z, const float* __restrict__ W1,
                         const float* __restrict__ b1, const float* __restrict__ W2,
                         float* __restrict__ wsum, int N) {
    __shared__ float W1s[D * 128];
    __shared__ float zs[16][D];
    int j = threadIdx.x; // 0..127 = hidden unit
    for (int k = j; k < D * 128; k += 128) W1s[k] = W1[k];
    int p = blockIdx.y;
    int n0 = blockIdx.x * 16;
    int nn = min(16, N - n0);
    const float* zb = z + ((size_t)p * N + n0) * D;
    for (int k = j; k < nn * D; k += 128) zs[k >> 6][k & (D - 1)] = zb[k];
    __syncthreads();
    float bj = b1[j], w2j = W2[j];
    float part = 0.f;
    for (int n = 0; n < nn; ++n) {
        float acc = bj;
#pragma unroll
        for (int k = 0; k < D; ++k) acc += zs[n][k] * W1s[k * 128 + j];
        part += tanhf(acc);
    }
    part *= w2j;
#pragma unroll
    for (int off = 32; off > 0; off >>= 1) part += __shfl_down(part, off, 64);
    __shared__ float ps[2];
    if ((j & 63) == 0) ps[j >> 6] = part;
    __syncthreads();
    if (j == 0) atomicAdd(&wsum[p], ps[0] + ps[1]);
}

// ---------------------------------------------------------------- beta = softmax(wsum / N)
__global__ void beta_k(const float* __restrict__ wsum, float* __restrict__ beta, float invN) {
    float w0 = wsum[0] * invN, w1 = wsum[1] * invN, w2 = wsum[2] * invN;
    float m = fmaxf(w0, fmaxf(w1, w2));
    float e0 = expf(w0 - m), e1 = expf(w1 - m), e2 = expf(w2 - m);
    float s = e0 + e1 + e2;
    beta[0] = e0 / s; beta[1] = e1 / s; beta[2] = e2 / s;
}

// ---------------------------------------------------------------- out = sum_p beta[p] * z[p]
__global__ void final_k(const float* __restrict__ z, const float* __restrict__ beta,
                        float* __restrict__ out, int n, size_t NF) {
    int i = blockIdx.x * blockDim.x + threadIdx.x;
    if (i < n) out[i] = beta[0] * z[i] + beta[1] * z[i + NF] + beta[2] * z[i + 2 * NF];
}

extern "C" void kernel_launch(void* const* d_in, const int* in_sizes, int n_in,
                              void* d_out, int out_size, void* d_ws, size_t ws_size,
                              hipStream_t stream) {
    const float* h   = (const float*)d_in[0];
    const int*   src = (const int*)d_in[1];
    const int*   dst = (const int*)d_in[2];
    const float* W1  = (const float*)d_in[3];
    const float* b1  = (const float*)d_in[4];
    const float* W2  = (const float*)d_in[5];

    const int P = 3;
    const int N = in_sizes[0] / D;          // 100000
    const int E = in_sizes[1] / P;          // 3200000
    const size_t NF = (size_t)N * D;        // 6.4M floats
    const int nf = (int)NF;
    const int NB = (N + 255) / 256;         // scan blocks (391 <= 512)

    // workspace layout (4B elems):
    // z[3*NF] | S[NF] | nout[N] | nin[N] | rowptr[N] | fillptr[N] | bsum[512] | ssrc[E] | sw[E] | wsum[4] | beta[4]
    float* ws      = (float*)d_ws;
    float* z       = ws;
    float* S       = ws + 3 * NF;
    float* nout    = ws + 4 * NF;
    float* nin     = nout + N;
    int*   rowptr  = (int*)(nin + N);
    int*   fillptr = rowptr + N;
    int*   bsum    = fillptr + N;
    int*   ssrc    = bsum + 512;
    float* sw      = (float*)(ssrc + E);
    float* wsum    = sw + E;
    float* beta    = wsum + 4;

    float* x = (float*)d_out; // d_out doubles as relu(h) buffer until final_k

    relu_k<<<(nf + 255) / 256, 256, 0, stream>>>(h, x, nf);

    for (int p = 0; p < P; ++p) {
        const int* sp = src + (size_t)p * E;
        const int* dp = dst + (size_t)p * E;

        hipMemsetAsync(nout, 0, 2 * (size_t)N * sizeof(float), stream);
        deg_k<<<(E + 255) / 256, 256, 0, stream>>>(sp, dp, nout, nin, E);
        // CSR build from in-degrees (read pre-norm float counts)
        scan1_k<<<NB, 256, 0, stream>>>(nin, rowptr, bsum, N);
        scan2_k<<<1, 512, 0, stream>>>(bsum, NB);
        scan3_k<<<NB, 256, 0, stream>>>(rowptr, fillptr, bsum, N);
        norm_k<<<(N + 255) / 256, 256, 0, stream>>>(nout, nin, N);
        reorder_k<<<(E + 255) / 256, 256, 0, stream>>>(sp, dp, nout, nin, fillptr, ssrc, sw, E);

        float* zp = z + (size_t)p * NF;
        // ping-pong: x -> zp -> S -> zp (result lands in zp)
        const float* fin[3]  = {x, zp, S};
        float*       fout[3] = {zp, S, zp};
        int pgrid = (N + 3) / 4; // 4 waves (nodes) per 256-thread block
        for (int step = 0; step < 3; ++step) {
            pull_k<<<pgrid, 256, 0, stream>>>(rowptr, fillptr, ssrc, sw, fin[step], x, fout[step], N);
        }
    }

    hipMemsetAsync(wsum, 0, 4 * sizeof(float), stream);
    dim3 fgrid((N + 15) / 16, P);
    fusion_k<<<fgrid, 128, 0, stream>>>(z, W1, b1, W2, wsum, N);
    beta_k<<<1, 1, 0, stream>>>(wsum, beta, 1.0f / (float)N);
    final_k<<<(nf + 255) / 256, 256, 0, stream>>>(z, beta, (float*)d_out, nf, NF);
}